// Round 12
// baseline (188.641 us; speedup 1.0000x reference)
//
#include <hip/hip_runtime.h>
#include <stdint.h>

// Volterra layer: out = conv3x3(x,w1) + conv3x3(quad,w2) + (b1 + 4*b2)
// quad = sum over 4 shifts of clip(x * circular_shift(x), -1, 1)
// B=8, C=64, H=W=256. Convs are zero-pad SAME; shifts are circular.

typedef short s16x8 __attribute__((ext_vector_type(8)));
typedef float f32x4 __attribute__((ext_vector_type(4)));

__device__ __forceinline__ float clip1(float v) { return fminf(fmaxf(v, -1.f), 1.f); }

__device__ __forceinline__ unsigned short f2bf(float f) {
    union { float f; unsigned u; } v; v.f = f;
    unsigned u = v.u;
    return (unsigned short)((u + 0x7fffu + ((u >> 16) & 1u)) >> 16);
}

__device__ __forceinline__ float bf2f(unsigned short u) {
    union { unsigned v; float f; } t; t.v = ((unsigned)u) << 16; return t.f;
}

// ---------------------------------------------------------------------------
// Kernel 1: weights -> bf16, layout Wb[kh][cc][co][kw*32+cci]
// ---------------------------------------------------------------------------
__global__ void prep_w(const float* __restrict__ w1, const float* __restrict__ w2,
                       unsigned short* __restrict__ Wb) {
    int idx = blockIdx.x * 256 + threadIdx.x;   // exactly 73728 threads
    int kk = idx % 96;
    int rest = idx / 96;
    int co = rest & 63; rest >>= 6;
    int cc = rest & 3;
    int kh = rest >> 2;
    int kw = kk >> 5;
    int cci = kk & 31;
    int c2 = cc * 32 + cci;
    const float* src = (c2 < 64) ? w1 : w2;
    int ci = c2 & 63;
    Wb[idx] = f2bf(src[((co * 64 + ci) * 3 + kh) * 3 + kw]);
}

// ---------------------------------------------------------------------------
// Kernel 2 (v4): quad/pack, channel-half split (R10 version).
// U[(b*256+h)*256+w][c2]: c2 0-63 = bf16(x), 64-127 = bf16(quad).
// ---------------------------------------------------------------------------
__global__ __launch_bounds__(512, 6) void prep_u4(const float* __restrict__ x,
                                                  unsigned short* __restrict__ U) {
    __shared__ unsigned short X[3][32][270];
    int bid = blockIdx.x;             // 4096 blocks
    int b = bid & 7;                  // image = XCD
    int rest = bid >> 3;              // 0..511
    int h = rest >> 1;
    int chunk = rest & 1;             // which 32-channel half
    int tid = threadIdx.x;

    for (int it = 0; it < 12; ++it) {
        int idx = tid + (it << 9);
        int w4 = idx & 63;
        int c  = (idx >> 6) & 31;
        int r  = idx >> 11;
        int gr = (h + r + 255) & 255;
        const float4 v = *(const float4*)(x + (((size_t)(b * 64 + chunk * 32 + c)) << 16)
                                            + (gr << 8) + (w4 << 2));
        ushort4 p;
        p.x = f2bf(v.x); p.y = f2bf(v.y); p.z = f2bf(v.z); p.w = f2bf(v.w);
        *(ushort4*)&X[r][c][w4 << 2] = p;
    }
    __syncthreads();

    int c  = tid & 31;
    int ph = (tid >> 5) & 1;
    int wv = tid >> 6;
    int p0 = (wv << 5) + (ph << 4);
    int pm0 = (p0 + 255) & 255;
    float pxc = bf2f(X[1][c][pm0]);
    float pxu = bf2f(X[0][c][pm0]);
    float pxd = bf2f(X[2][c][pm0]);
    size_t base = ((size_t)(((b << 8) + h))) << 8;
    int cx = chunk * 32 + c;
#pragma unroll 4
    for (int i = 0; i < 16; ++i) {
        int p = p0 + i;
        unsigned short xcb = X[1][c][p];
        float xc = bf2f(xcb);
        float xu = bf2f(X[0][c][p]);
        float xd = bf2f(X[2][c][p]);
        float q = clip1(xc * xu) + clip1(xc * pxd) + clip1(xc * pxc) + clip1(xc * pxu);
        size_t po = (base + p) << 7;
        U[po + cx]      = xcb;
        U[po + 64 + cx] = f2bf(q);
        pxc = xc; pxu = xu; pxd = xd;
    }
}

// ---------------------------------------------------------------------------
// Kernel 3 (v9): input-row-stationary conv, LONGER row pipeline.
// Block = 8 output rows x 64 px, 512 thr = 8 waves; wave = one output row
// (64co x 64px tile, acc[4][4]). Per cc: 10 row-stages serve 8 rows
// (1.25 stages/row vs conv5's 1.5). kh = j - rowsel (valid 0..2).
// LDS: Alds[3][64][104] 39.9KB + Ib[2][66][40] 10.6KB = 50.5KB;
// regs 128/wave -> 4 waves/SIMD -> 2 resident blocks/CU (16 waves).
// Proven conflict-free strides (104/40 per 16-lane phase), T14 early-issue.
// ---------------------------------------------------------------------------
__global__ __launch_bounds__(512, 4) void conv9(
        const unsigned short* __restrict__ U,
        const unsigned short* __restrict__ Wb,
        const float* __restrict__ b1, const float* __restrict__ b2,
        float* __restrict__ out) {
    __shared__ unsigned short Alds[3][64][104];   // 39936 B
    __shared__ unsigned short Ib[2][66][40];      // 10560 B  (total 50496 B)

    int bid = blockIdx.x;                          // 1024 blocks
    int logical = ((bid & 7) << 7) + (bid >> 3);   // XCD k -> batch image k
    int b = logical >> 7;
    int rem = logical & 127;                       // 32 row-groups x 4 col-quarters
    int h0 = (rem >> 2) << 3;                      // 8 output rows h0..h0+7
    int wq = rem & 3;
    int w0 = wq << 6;                              // 64-px column base
    int tid = threadIdx.x;
    int wid = tid >> 6;
    int ln = tid & 63;
    int lr = ln & 15;        // MFMA A-row / C col
    int lq = ln >> 4;        // MFMA k-group / C row-group
    int rowsel = wid;        // wave = output row h0+rowsel
    int o = h0 + rowsel;

    f32x4 acc[4][4];
#pragma unroll
    for (int m = 0; m < 4; m++)
#pragma unroll
        for (int n = 0; n < 4; n++) {
            acc[m][n][0] = 0.f; acc[m][n][1] = 0.f; acc[m][n][2] = 0.f; acc[m][n][3] = 0.f;
        }

    const size_t ubase = ((size_t)b) << 23;

    int cur = 0;
    for (int cc = 0; cc < 4; cc++) {
        // ---- stage weights for all 3 kh of this cc
        for (int i = tid; i < 2304; i += 512) {
            int kh = i / 768;
            int remw = i - kh * 768;
            int co = remw / 12;
            int kk = (remw - co * 12) << 3;
            *(uint4*)&Alds[kh][co][kk] =
                *(const uint4*)&Wb[(((size_t)((kh * 4 + cc) * 64 + co)) * 96) + kk];
        }
        // ---- stage input row j=0 (r = h0-1) into Ib[cur]: 66 px x 4 quads
        {
            int r = h0 - 1;
            if (r >= 0) {
                const unsigned short* usrc = U + ubase + (((size_t)r) << 15) + cc * 32;
                if (tid < 264) {
                    int p = tid >> 2, q = tid & 3;
                    int gcol = w0 + p - 1;
                    uint4 v = (gcol < 0 || gcol > 255) ? make_uint4(0u, 0u, 0u, 0u)
                              : *(const uint4*)&usrc[(((size_t)gcol) << 7) + q * 8];
                    *(uint4*)&Ib[cur][p][q * 8] = v;
                }
            }
        }
        __syncthreads();

        for (int j = 0; j < 10; j++) {
            // ---- early-issue loads for next input row (hidden under compute)
            int rn = h0 + j;              // row staged for iteration j+1
            bool have = (j < 9) && (rn <= 255) && (tid < 264);
            uint4 s0;
            if (have) {
                const unsigned short* usrc = U + ubase + (((size_t)rn) << 15) + cc * 32;
                int p = tid >> 2, q = tid & 3;
                int gcol = w0 + p - 1;
                s0 = (gcol < 0 || gcol > 255) ? make_uint4(0u, 0u, 0u, 0u)
                     : *(const uint4*)&usrc[(((size_t)gcol) << 7) + q * 8];
            }
            // ---- compute stage j: input row r = h0-1+j, this wave's kh = j-rowsel
            int r = h0 - 1 + j;
            int kh = j - rowsel;
            if (kh >= 0 && kh <= 2 && r >= 0 && r <= 255) {
                __builtin_amdgcn_s_setprio(1);
#pragma unroll
                for (int kw = 0; kw < 3; kw++) {
                    s16x8 af[4], bfr[4];
#pragma unroll
                    for (int m = 0; m < 4; m++)
                        af[m] = *(const s16x8*)&Alds[kh][m * 16 + lr][kw * 32 + lq * 8];
#pragma unroll
                    for (int n = 0; n < 4; n++)
                        bfr[n] = *(const s16x8*)&Ib[cur][n * 16 + lr + kw][lq * 8];
#pragma unroll
                    for (int m = 0; m < 4; m++)
#pragma unroll
                        for (int n = 0; n < 4; n++)
                            acc[m][n] = __builtin_amdgcn_mfma_f32_16x16x32_bf16(af[m], bfr[n], acc[m][n], 0, 0, 0);
                }
                __builtin_amdgcn_s_setprio(0);
            }
            // ---- write staged regs into the other buffer
            if (have) {
                int p = tid >> 2, q = tid & 3;
                *(uint4*)&Ib[cur ^ 1][p][q * 8] = s0;
            }
            __syncthreads();
            if (j < 9) cur ^= 1;
        }
    }

    // epilogue: C/D layout col=lane&15 (pixel), row=(lane>>4)*4+jj (cout)
#pragma unroll
    for (int m = 0; m < 4; m++) {
#pragma unroll
        for (int jj = 0; jj < 4; jj++) {
            int co = m * 16 + lq * 4 + jj;
            float bias = b1[co] + 4.f * b2[co];
#pragma unroll
            for (int n = 0; n < 4; n++) {
                int wpix = w0 + n * 16 + lr;
                out[(((size_t)(b * 64 + co)) << 16) + (o << 8) + wpix] = acc[m][n][jj] + bias;
            }
        }
    }
}

// ---------------------------------------------------------------------------
// Fallback (only if ws too small): direct conv, recomputing quad on the fly.
// ---------------------------------------------------------------------------
__global__ void fallback_conv(const float* __restrict__ x,
                              const float* __restrict__ w1, const float* __restrict__ b1,
                              const float* __restrict__ w2, const float* __restrict__ b2,
                              float* __restrict__ out) {
    size_t idx = (size_t)blockIdx.x * 256 + threadIdx.x;
    int w = idx & 255;
    int h = (int)(idx >> 8) & 255;
    int co = (int)(idx >> 16) & 63;
    int b = (int)(idx >> 22);
    float acc = b1[co] + 4.f * b2[co];
    const float* xb = x + (((size_t)b * 64) << 16);
    for (int ci = 0; ci < 64; ci++) {
        const float* xp = xb + (((size_t)ci) << 16);
        for (int kh = 0; kh < 3; kh++) {
            int hh = h + kh - 1;
            if (hh < 0 || hh > 255) continue;
            for (int kw = 0; kw < 3; kw++) {
                int ww = w + kw - 1;
                if (ww < 0 || ww > 255) continue;
                float xv = xp[(hh << 8) + ww];
                float g1 = w1[((co * 64 + ci) * 3 + kh) * 3 + kw];
                float g2 = w2[((co * 64 + ci) * 3 + kh) * 3 + kw];
                int hm = (hh + 255) & 255, hp = (hh + 1) & 255, wm = (ww + 255) & 255;
                float q = clip1(xv * xp[(hm << 8) + ww]) + clip1(xv * xp[(hp << 8) + wm])
                        + clip1(xv * xp[(hh << 8) + wm]) + clip1(xv * xp[(hm << 8) + wm]);
                acc = fmaf(g1, xv, acc);
                acc = fmaf(g2, q, acc);
            }
        }
    }
    out[idx] = acc;
}

extern "C" void kernel_launch(void* const* d_in, const int* in_sizes, int n_in,
                              void* d_out, int out_size, void* d_ws, size_t ws_size,
                              hipStream_t stream) {
    const float* x  = (const float*)d_in[0];
    const float* w1 = (const float*)d_in[1];
    const float* b1 = (const float*)d_in[2];
    const float* w2 = (const float*)d_in[3];
    const float* b2 = (const float*)d_in[4];
    float* out = (float*)d_out;

    const size_t WB_BYTES = 262144;
    const size_t U_BYTES  = (size_t)8 * 256 * 256 * 128 * 2;  // 128 MiB
    if (ws_size >= WB_BYTES + U_BYTES) {
        unsigned short* Wb = (unsigned short*)d_ws;
        unsigned short* U  = (unsigned short*)((char*)d_ws + WB_BYTES);
        prep_w<<<dim3(288), dim3(256), 0, stream>>>(w1, w2, Wb);
        prep_u4<<<dim3(4096), dim3(512), 0, stream>>>(x, U);
        conv9<<<dim3(1024), dim3(512), 0, stream>>>(U, Wb, b1, b2, out);
    } else {
        fallback_conv<<<dim3(131072), dim3(256), 0, stream>>>(x, w1, b1, w2, b2, out);
    }
}

// Round 14
// 162.438 us; speedup vs baseline: 1.1613x; 1.1613x over previous
//
#include <hip/hip_runtime.h>
#include <stdint.h>

// Volterra layer: out = conv3x3(x,w1) + conv3x3(quad,w2) + (b1 + 4*b2)
// quad = sum over 4 shifts of clip(x * circular_shift(x), -1, 1)
// B=8, C=64, H=W=256. Convs are zero-pad SAME; shifts are circular.

typedef short s16x8 __attribute__((ext_vector_type(8)));
typedef float f32x4 __attribute__((ext_vector_type(4)));

__device__ __forceinline__ float clip1(float v) { return fminf(fmaxf(v, -1.f), 1.f); }

__device__ __forceinline__ unsigned short f2bf(float f) {
    union { float f; unsigned u; } v; v.f = f;
    unsigned u = v.u;
    return (unsigned short)((u + 0x7fffu + ((u >> 16) & 1u)) >> 16);
}

__device__ __forceinline__ float bf2f(unsigned short u) {
    union { unsigned v; float f; } t; t.v = ((unsigned)u) << 16; return t.f;
}

// ---------------------------------------------------------------------------
// Kernel 1: weights -> bf16, layout Wb[kh][cc][co][kw*32+cci]
// ---------------------------------------------------------------------------
__global__ void prep_w(const float* __restrict__ w1, const float* __restrict__ w2,
                       unsigned short* __restrict__ Wb) {
    int idx = blockIdx.x * 256 + threadIdx.x;   // exactly 73728 threads
    int kk = idx % 96;
    int rest = idx / 96;
    int co = rest & 63; rest >>= 6;
    int cc = rest & 3;
    int kh = rest >> 2;
    int kw = kk >> 5;
    int cci = kk & 31;
    int c2 = cc * 32 + cci;
    const float* src = (c2 < 64) ? w1 : w2;
    int ci = c2 & 63;
    Wb[idx] = f2bf(src[((co * 64 + ci) * 3 + kh) * 3 + kw]);
}

// ---------------------------------------------------------------------------
// Kernel 2 (v4): quad/pack, channel-half split (R10 version, ~HBM floor).
// U[(b*256+h)*256+w][c2]: c2 0-63 = bf16(x), 64-127 = bf16(quad).
// ---------------------------------------------------------------------------
__global__ __launch_bounds__(512, 6) void prep_u4(const float* __restrict__ x,
                                                  unsigned short* __restrict__ U) {
    __shared__ unsigned short X[3][32][270];
    int bid = blockIdx.x;             // 4096 blocks
    int b = bid & 7;                  // image = XCD
    int rest = bid >> 3;              // 0..511
    int h = rest >> 1;
    int chunk = rest & 1;             // which 32-channel half
    int tid = threadIdx.x;

    for (int it = 0; it < 12; ++it) {
        int idx = tid + (it << 9);
        int w4 = idx & 63;
        int c  = (idx >> 6) & 31;
        int r  = idx >> 11;
        int gr = (h + r + 255) & 255;
        const float4 v = *(const float4*)(x + (((size_t)(b * 64 + chunk * 32 + c)) << 16)
                                            + (gr << 8) + (w4 << 2));
        ushort4 p;
        p.x = f2bf(v.x); p.y = f2bf(v.y); p.z = f2bf(v.z); p.w = f2bf(v.w);
        *(ushort4*)&X[r][c][w4 << 2] = p;
    }
    __syncthreads();

    int c  = tid & 31;
    int ph = (tid >> 5) & 1;
    int wv = tid >> 6;
    int p0 = (wv << 5) + (ph << 4);
    int pm0 = (p0 + 255) & 255;
    float pxc = bf2f(X[1][c][pm0]);
    float pxu = bf2f(X[0][c][pm0]);
    float pxd = bf2f(X[2][c][pm0]);
    size_t base = ((size_t)(((b << 8) + h))) << 8;
    int cx = chunk * 32 + c;
#pragma unroll 4
    for (int i = 0; i < 16; ++i) {
        int p = p0 + i;
        unsigned short xcb = X[1][c][p];
        float xc = bf2f(xcb);
        float xu = bf2f(X[0][c][p]);
        float xd = bf2f(X[2][c][p]);
        float q = clip1(xc * xu) + clip1(xc * pxd) + clip1(xc * pxc) + clip1(xc * pxu);
        size_t po = (base + p) << 7;
        U[po + cx]      = xcb;
        U[po + 64 + cx] = f2bf(q);
        pxc = xc; pxu = xu; pxd = xd;
    }
}

// ---------------------------------------------------------------------------
// Kernel 3 (v10b): conv5 geometry, TWO input rows per stage. FIXED staging
// semantics: writes are gated ONLY by row validity; out-of-range lanes write
// ZEROS (zero-pad SAME), exactly like conv5.
// Per cc: 3 stages x 2 rows; barriers/block 28 -> 16; duty 66%.
// LDS: Alds 39.9KB + Ib[2][2][130][40] 41.6KB = 81.5KB -> 2 blocks/CU.
// ---------------------------------------------------------------------------
__global__ __launch_bounds__(512, 4) void conv10(
        const unsigned short* __restrict__ U,
        const unsigned short* __restrict__ Wb,
        const float* __restrict__ b1, const float* __restrict__ b2,
        float* __restrict__ out) {
    __shared__ unsigned short Alds[3][64][104];   // 39936 B
    __shared__ unsigned short Ib[2][2][130][40];  // 41600 B  (total 81536 B)

    int bid = blockIdx.x;                          // 1024 blocks
    int logical = ((bid & 7) << 7) + (bid >> 3);   // XCD k -> batch image k
    int b = logical >> 7;
    int rem = logical & 127;
    int h0 = (rem >> 1) << 2;                      // 4 output rows h0..h0+3
    int whalf = rem & 1;
    int w0 = whalf << 7;                           // pixel-half base 0 / 128
    int tid = threadIdx.x;
    int wid = tid >> 6;
    int ln = tid & 63;
    int lr = ln & 15;        // MFMA A-row / C col
    int lq = ln >> 4;        // MFMA k-group / C row-group
    int rowsel = wid >> 1;   // which of the 4 output rows
    int pq = wid & 1;        // pixel 64-quarter within the 128-px half
    int o = h0 + rowsel;

    f32x4 acc[4][4];
#pragma unroll
    for (int m = 0; m < 4; m++)
#pragma unroll
        for (int n = 0; n < 4; n++) {
            acc[m][n][0] = 0.f; acc[m][n][1] = 0.f; acc[m][n][2] = 0.f; acc[m][n][3] = 0.f;
        }

    const size_t ubase = ((size_t)b) << 23;
    int sp = tid >> 2, sq = tid & 3;               // staging (px, quad)
    int sgcol = w0 + sp - 1;                       // main-load column
    bool smain_ok = (sgcol >= 0 && sgcol <= 255);  // lane validity (data select)

    // prologue: stage rows h0-1, h0 (cc=0) into buffer 0; OOB lanes/rows -> 0
    {
        for (int rr = 0; rr < 2; ++rr) {
            int r = h0 - 1 + rr;
            uint4 v = make_uint4(0u, 0u, 0u, 0u);
            if (r >= 0 && smain_ok)
                v = *(const uint4*)(U + ubase + (((size_t)r) << 15)
                                    + (((size_t)sgcol) << 7) + sq * 8);
            *(uint4*)&Ib[0][rr][sp][sq * 8] = v;
        }
        if (tid < 8) {
            int i2 = tid + 512;
            int p = i2 >> 2, q = i2 & 3;
            int gcol = w0 + p - 1;
            for (int rr = 0; rr < 2; ++rr) {
                int r = h0 - 1 + rr;
                uint4 t = (r < 0 || gcol > 255) ? make_uint4(0u, 0u, 0u, 0u)
                          : *(const uint4*)(U + ubase + (((size_t)r) << 15)
                                            + (((size_t)gcol) << 7) + q * 8);
                *(uint4*)&Ib[0][rr][p][q * 8] = t;
            }
        }
    }

    int cur = 0;
    for (int cc = 0; cc < 4; cc++) {
        int ccoff = cc * 32;
        // ---- stage weights for all 3 kh of this cc
        for (int i = tid; i < 2304; i += 512) {
            int kh = i / 768;
            int remw = i - kh * 768;
            int co = remw / 12;
            int kk = (remw - co * 12) << 3;
            *(uint4*)&Alds[kh][co][kk] =
                *(const uint4*)&Wb[(((size_t)((kh * 4 + cc) * 64 + co)) * 96) + kk];
        }
        __syncthreads();   // weights + prologue/prefetched rows visible

        for (int s = 0; s < 3; s++) {
            // ---- early-issue next-stage rows (same cc s<2; next cc at s==2)
            int nr0, nr1, noff;
            bool last = (s == 2);
            bool havestage = !last || (cc < 3);
            if (!last) { nr0 = h0 + 1 + 2 * s; nr1 = nr0 + 1; noff = ccoff; }
            else       { nr0 = h0 - 1;        nr1 = h0;      noff = ccoff + 32; }
            // row validity gates the WRITE; lane validity only selects zero data
            bool rowA = havestage && nr0 >= 0 && nr0 <= 255;
            bool rowB = havestage && nr1 >= 0 && nr1 <= 255;
            uint4 sA = make_uint4(0u, 0u, 0u, 0u), sB = make_uint4(0u, 0u, 0u, 0u);
            if (rowA && smain_ok)
                sA = *(const uint4*)(U + ubase + (((size_t)nr0) << 15)
                                     + (((size_t)sgcol) << 7) + noff + sq * 8);
            if (rowB && smain_ok)
                sB = *(const uint4*)(U + ubase + (((size_t)nr1) << 15)
                                     + (((size_t)sgcol) << 7) + noff + sq * 8);
            // ---- compute stage s: rows h0-1+2s (rr=0), h0+2s (rr=1)
            int base2 = 2 * s;
#pragma unroll
            for (int kh = 0; kh < 3; kh++) {
                int t = rowsel + kh;
                int r = h0 - 1 + t;
                if (t >= base2 && t <= base2 + 1 && r >= 0 && r <= 255) {
                    int rr = t - base2;
                    __builtin_amdgcn_s_setprio(1);
#pragma unroll
                    for (int kw = 0; kw < 3; kw++) {
                        s16x8 af[4], bfr[4];
#pragma unroll
                        for (int m = 0; m < 4; m++)
                            af[m] = *(const s16x8*)&Alds[kh][m * 16 + lr][kw * 32 + lq * 8];
#pragma unroll
                        for (int n = 0; n < 4; n++)
                            bfr[n] = *(const s16x8*)&Ib[cur][rr][(pq << 6) + n * 16 + lr + kw][lq * 8];
#pragma unroll
                        for (int m = 0; m < 4; m++)
#pragma unroll
                            for (int n = 0; n < 4; n++)
                                acc[m][n] = __builtin_amdgcn_mfma_f32_16x16x32_bf16(af[m], bfr[n], acc[m][n], 0, 0, 0);
                    }
                    __builtin_amdgcn_s_setprio(0);
                }
            }
            // ---- write prefetched rows into the other buffer (+ tails)
            if (rowA) *(uint4*)&Ib[cur ^ 1][0][sp][sq * 8] = sA;
            if (rowB) *(uint4*)&Ib[cur ^ 1][1][sp][sq * 8] = sB;
            if (havestage && tid < 8) {
                int i2 = tid + 512;
                int p = i2 >> 2, q = i2 & 3;
                int gcol = w0 + p - 1;
                for (int rr = 0; rr < 2; ++rr) {
                    int r = (rr == 0) ? nr0 : nr1;
                    if (r < 0 || r > 255) continue;
                    uint4 t = (gcol > 255) ? make_uint4(0u, 0u, 0u, 0u)
                              : *(const uint4*)(U + ubase + (((size_t)r) << 15)
                                                + (((size_t)gcol) << 7) + noff + q * 8);
                    *(uint4*)&Ib[cur ^ 1][rr][p][q * 8] = t;
                }
            }
            __syncthreads();
            cur ^= 1;
        }
    }

    // epilogue: C/D layout col=lane&15 (pixel), row=(lane>>4)*4+jj (cout)
#pragma unroll
    for (int m = 0; m < 4; m++) {
#pragma unroll
        for (int jj = 0; jj < 4; jj++) {
            int co = m * 16 + lq * 4 + jj;
            float bias = b1[co] + 4.f * b2[co];
#pragma unroll
            for (int n = 0; n < 4; n++) {
                int wpix = w0 + (pq << 6) + n * 16 + lr;
                out[(((size_t)(b * 64 + co)) << 16) + (o << 8) + wpix] = acc[m][n][jj] + bias;
            }
        }
    }
}

// ---------------------------------------------------------------------------
// Fallback (only if ws too small): direct conv, recomputing quad on the fly.
// ---------------------------------------------------------------------------
__global__ void fallback_conv(const float* __restrict__ x,
                              const float* __restrict__ w1, const float* __restrict__ b1,
                              const float* __restrict__ w2, const float* __restrict__ b2,
                              float* __restrict__ out) {
    size_t idx = (size_t)blockIdx.x * 256 + threadIdx.x;
    int w = idx & 255;
    int h = (int)(idx >> 8) & 255;
    int co = (int)(idx >> 16) & 63;
    int b = (int)(idx >> 22);
    float acc = b1[co] + 4.f * b2[co];
    const float* xb = x + (((size_t)b * 64) << 16);
    for (int ci = 0; ci < 64; ci++) {
        const float* xp = xb + (((size_t)ci) << 16);
        for (int kh = 0; kh < 3; kh++) {
            int hh = h + kh - 1;
            if (hh < 0 || hh > 255) continue;
            for (int kw = 0; kw < 3; kw++) {
                int ww = w + kw - 1;
                if (ww < 0 || ww > 255) continue;
                float xv = xp[(hh << 8) + ww];
                float g1 = w1[((co * 64 + ci) * 3 + kh) * 3 + kw];
                float g2 = w2[((co * 64 + ci) * 3 + kh) * 3 + kw];
                int hm = (hh + 255) & 255, hp = (hh + 1) & 255, wm = (ww + 255) & 255;
                float q = clip1(xv * xp[(hm << 8) + ww]) + clip1(xv * xp[(hp << 8) + wm])
                        + clip1(xv * xp[(hh << 8) + wm]) + clip1(xv * xp[(hm << 8) + wm]);
                acc = fmaf(g1, xv, acc);
                acc = fmaf(g2, q, acc);
            }
        }
    }
    out[idx] = acc;
}

extern "C" void kernel_launch(void* const* d_in, const int* in_sizes, int n_in,
                              void* d_out, int out_size, void* d_ws, size_t ws_size,
                              hipStream_t stream) {
    const float* x  = (const float*)d_in[0];
    const float* w1 = (const float*)d_in[1];
    const float* b1 = (const float*)d_in[2];
    const float* w2 = (const float*)d_in[3];
    const float* b2 = (const float*)d_in[4];
    float* out = (float*)d_out;

    const size_t WB_BYTES = 262144;
    const size_t U_BYTES  = (size_t)8 * 256 * 256 * 128 * 2;  // 128 MiB
    if (ws_size >= WB_BYTES + U_BYTES) {
        unsigned short* Wb = (unsigned short*)d_ws;
        unsigned short* U  = (unsigned short*)((char*)d_ws + WB_BYTES);
        prep_w<<<dim3(288), dim3(256), 0, stream>>>(w1, w2, Wb);
        prep_u4<<<dim3(4096), dim3(512), 0, stream>>>(x, U);
        conv10<<<dim3(1024), dim3(512), 0, stream>>>(U, Wb, b1, b2, out);
    } else {
        fallback_conv<<<dim3(131072), dim3(256), 0, stream>>>(x, w1, b1, w2, b2, out);
    }
}